// Round 2
// baseline (17900.714 us; speedup 1.0000x reference)
//
#include <hip/hip_runtime.h>

// GhostGRU persistent-RNN kernel for MI355X (gfx950).
// Inputs/outputs are fp32 (per reference); internal matmuls bf16 MFMA with
// fp32 accumulation; recurrent state and u-gate kept fp32.
// 8 independent batch-groups (16 batches each) x 32 WGs; weights VGPR-resident;
// 3 group barriers per time step; MFMA f32_16x16x32_bf16, M=16=batch tile.

typedef unsigned short ushort_t;
typedef __attribute__((ext_vector_type(8))) short short8;   // 8 x bf16 (4 VGPRs)
typedef __attribute__((ext_vector_type(4))) float f32x4;

#define NB 128
#define NT 512
#define NF 256
#define NH 1024
#define KGATE 1280

__device__ __forceinline__ float bf2f(ushort_t u) {
  union { unsigned int i; float f; } v; v.i = ((unsigned int)u) << 16; return v.f;
}
__device__ __forceinline__ ushort_t f2bf(float f) {
  union { float f; unsigned int i; } v; v.f = f;
  unsigned int r = v.i + 0x7FFFu + ((v.i >> 16) & 1u);
  return (ushort_t)(r >> 16);
}
__device__ __forceinline__ float sigmoidf_(float x) { return 1.f / (1.f + __expf(-x)); }
__device__ __forceinline__ float tanhf_(float x) {
  float e = __expf(2.f * x); return 1.f - 2.f / (e + 1.f);
}

// Monotonic-counter group barrier among 32 WGs (one counter line per group).
__device__ __forceinline__ void group_barrier(unsigned int* cnt, unsigned int target) {
  __syncthreads();  // drains all waves' vmem (compiler emits vmcnt(0) before s_barrier)
  if (threadIdx.x == 0) {
    __hip_atomic_fetch_add(cnt, 1u, __ATOMIC_RELEASE, __HIP_MEMORY_SCOPE_AGENT);
    while (__hip_atomic_load(cnt, __ATOMIC_RELAXED, __HIP_MEMORY_SCOPE_AGENT) < target) { }
    __threadfence();  // acquire: make remote writes visible to this CU
  }
  __syncthreads();
}

__device__ __forceinline__ short8 pack_bf16_8(const float* p) {
  float4 a = *(const float4*)p;
  float4 b = *(const float4*)(p + 4);
  short8 f;
  f[0] = (short)f2bf(a.x); f[1] = (short)f2bf(a.y);
  f[2] = (short)f2bf(a.z); f[3] = (short)f2bf(a.w);
  f[4] = (short)f2bf(b.x); f[5] = (short)f2bf(b.y);
  f[6] = (short)f2bf(b.z); f[7] = (short)f2bf(b.w);
  return f;
}

__global__ void __launch_bounds__(256, 1) ghost_gru_persistent(
    const float* __restrict__ x, const float* __restrict__ hidden,
    const float* __restrict__ Wg, const float* __restrict__ Wc,
    const float* __restrict__ Wgh, const float* __restrict__ bg,
    const float* __restrict__ bc, const float* __restrict__ bgh,
    float* __restrict__ out, ushort_t* __restrict__ hbuf,
    ushort_t* __restrict__ rsbuf, float* __restrict__ ubuf,
    unsigned int* __restrict__ counters)
{
  const int wgid = blockIdx.x;
  const int g    = wgid & 7;      // group (XCD-affine heuristic)
  const int memb = wgid >> 3;     // member 0..31 within group
  const int b0   = g * 16;        // batch base
  const int tid  = threadIdx.x;
  const int wv   = tid >> 6;      // wave 0..3
  const int lane = tid & 63;
  const int lq   = lane >> 4;     // quad 0..3
  const int ln   = lane & 15;
  unsigned int* cnt = counters + g * 32;

  // A-staging (bf16): [16 batches][ x(0..255) | ghost(256..767) | newh(768..1279) | rstate(1280..1791) | pad ]
  __shared__ ushort_t Abuf[16][1800];

  // VGPR-resident weight fragments: B-frag lane (n + 16q) holds W[n][kc*32 + 8q .. +7]
  short8 wfrag[40];
  int ncol0;
  float biasv;
  if (wv == 0 || wv == 1) {                    // gate: 32 cols per WG, 16 per wave
    ncol0 = memb * 32 + wv * 16;
    const float* wp = Wg + (size_t)(ncol0 + ln) * KGATE + lq * 8;
    #pragma unroll
    for (int kc = 0; kc < 40; ++kc) wfrag[kc] = pack_bf16_8(wp + kc * 32);
    biasv = bg[ncol0 + ln];
  } else if (wv == 2) {                        // candidate: 16 cols
    ncol0 = memb * 16;
    const float* wp = Wc + (size_t)(ncol0 + ln) * KGATE + lq * 8;
    #pragma unroll
    for (int kc = 0; kc < 40; ++kc) wfrag[kc] = pack_bf16_8(wp + kc * 32);
    biasv = bc[ncol0 + ln];
  } else {                                     // ghost: 16 cols, K=512
    ncol0 = memb * 16;
    const float* wp = Wgh + (size_t)(ncol0 + ln) * 512 + lq * 8;
    #pragma unroll
    for (int kc = 0; kc < 16; ++kc) wfrag[kc] = pack_bf16_8(wp + kc * 32);
    biasv = bgh[ncol0 + ln];
  }

  // fp32 master copy of new_h state, held by cand wave across all steps.
  float hreg[4];
  if (wv == 2) {
    #pragma unroll
    for (int r = 0; r < 4; ++r)
      hreg[r] = hidden[(size_t)(b0 + lq * 4 + r) * NH + 512 + ncol0 + ln];
  }

  for (int t = 0; t < NT; ++t) {
    const int cur = t & 1, nxt = cur ^ 1;

    // ---- stage x_t (16x256 fp32 -> bf16) and h=[ghost,newh] (16x1024 bf16) ----
    for (int i = tid; i < 1024; i += 256) {
      int row = i >> 6, c4 = (i & 63) * 4;
      float4 v = *(const float4*)&x[((size_t)(b0 + row) * NT + t) * NF + c4];
      ushort_t u0 = f2bf(v.x), u1 = f2bf(v.y), u2 = f2bf(v.z), u3 = f2bf(v.w);
      ushort4 u4 = make_ushort4(u0, u1, u2, u3);
      *(ushort4*)&Abuf[row][c4] = u4;
    }
    const ushort_t* hsrc = hbuf + (size_t)cur * NB * NH;
    for (int i = tid; i < 2048; i += 256) {
      int row = i >> 7, c = i & 127;
      *(uint4*)&Abuf[row][256 + c * 8] =
          *(const uint4*)&hsrc[(size_t)(b0 + row) * NH + c * 8];
    }
    __syncthreads();

    // ---- phase 1: gate = sigmoid([x,ghost,newh] @ Wg^T + bg) ----
    if (wv < 2) {
      f32x4 acc0 = {0.f, 0.f, 0.f, 0.f}, acc1 = {0.f, 0.f, 0.f, 0.f};
      #pragma unroll
      for (int kc = 0; kc < 40; kc += 2) {
        short8 a0 = *(const short8*)&Abuf[ln][kc * 32 + lq * 8];
        acc0 = __builtin_amdgcn_mfma_f32_16x16x32_bf16(a0, wfrag[kc], acc0, 0, 0, 0);
        short8 a1 = *(const short8*)&Abuf[ln][(kc + 1) * 32 + lq * 8];
        acc1 = __builtin_amdgcn_mfma_f32_16x16x32_bf16(a1, wfrag[kc + 1], acc1, 0, 0, 0);
      }
      const int n = ncol0 + ln;
      #pragma unroll
      for (int r = 0; r < 4; ++r) {
        int row = lq * 4 + r;
        float s = sigmoidf_(acc0[r] + acc1[r] + biasv);
        if (ncol0 < 512) {  // r-gate -> rstate = r * h_old[newh part]
          float hold = bf2f(Abuf[row][768 + n]);
          rsbuf[(size_t)(b0 + row) * 512 + n] = f2bf(s * hold);
        } else {            // u-gate (fp32 for state update)
          ubuf[(size_t)(b0 + row) * 512 + (n - 512)] = s;
        }
      }
    }
    group_barrier(cnt, 32u * (3u * (unsigned)t + 1u));

    // ---- stage rstate (16x512 bf16) ----
    for (int i = tid; i < 1024; i += 256) {
      int row = i >> 6, c = i & 63;
      *(uint4*)&Abuf[row][1280 + c * 8] =
          *(const uint4*)&rsbuf[(size_t)(b0 + row) * 512 + c * 8];
    }
    __syncthreads();

    ushort_t* hdst = hbuf + (size_t)nxt * NB * NH;

    // ---- phase 2: c = tanh([x,ghost,rstate] @ Wc^T + bc); new_h = u*h + (1-u)*c ----
    if (wv == 2) {
      f32x4 acc0 = {0.f, 0.f, 0.f, 0.f}, acc1 = {0.f, 0.f, 0.f, 0.f};
      #pragma unroll
      for (int kc = 0; kc < 40; kc += 2) {
        int base0 = (kc < 24) ? kc * 32 : 1280 + (kc - 24) * 32;
        int base1 = (kc + 1 < 24) ? (kc + 1) * 32 : 1280 + (kc + 1 - 24) * 32;
        short8 a0 = *(const short8*)&Abuf[ln][base0 + lq * 8];
        acc0 = __builtin_amdgcn_mfma_f32_16x16x32_bf16(a0, wfrag[kc], acc0, 0, 0, 0);
        short8 a1 = *(const short8*)&Abuf[ln][base1 + lq * 8];
        acc1 = __builtin_amdgcn_mfma_f32_16x16x32_bf16(a1, wfrag[kc + 1], acc1, 0, 0, 0);
      }
      const int n = ncol0 + ln;
      #pragma unroll
      for (int r = 0; r < 4; ++r) {
        int row = lq * 4 + r;
        int b = b0 + row;
        float cv = tanhf_(acc0[r] + acc1[r] + biasv);
        float u = ubuf[(size_t)b * 512 + n];
        float hnew = u * hreg[r] + (1.f - u) * cv;
        hreg[r] = hnew;
        out[((size_t)b * NT + t) * NH + 512 + n] = hnew;
        hdst[(size_t)b * NH + 512 + n] = f2bf(hnew);
        if (t == NT - 1) out[(size_t)NB * NT * NH + (size_t)b * NH + 512 + n] = hnew;
      }
    }
    group_barrier(cnt, 32u * (3u * (unsigned)t + 2u));

    // ---- phase 3: ghost = tanh(new_h @ Wgh^T + bgh) ----
    if (wv == 3) {
      f32x4 acc = {0.f, 0.f, 0.f, 0.f};
      const ushort_t* hp = hdst + (size_t)(b0 + ln) * NH + 512 + lq * 8;
      #pragma unroll
      for (int kc = 0; kc < 16; ++kc) {
        short8 a = *(const short8*)(hp + kc * 32);  // gather fresh new_h from L2/L3
        acc = __builtin_amdgcn_mfma_f32_16x16x32_bf16(a, wfrag[kc], acc, 0, 0, 0);
      }
      const int n = ncol0 + ln;
      #pragma unroll
      for (int r = 0; r < 4; ++r) {
        int row = lq * 4 + r;
        int b = b0 + row;
        float gv = tanhf_(acc[r] + biasv);
        out[((size_t)b * NT + t) * NH + n] = gv;
        hdst[(size_t)b * NH + n] = f2bf(gv);
        if (t == NT - 1) out[(size_t)NB * NT * NH + (size_t)b * NH + n] = gv;
      }
    }
    group_barrier(cnt, 32u * (3u * (unsigned)t + 3u));
  }
}

__global__ void init_kernel(const float* __restrict__ hidden,
                            ushort_t* __restrict__ hbuf,
                            unsigned int* __restrict__ counters) {
  int i = blockIdx.x * blockDim.x + threadIdx.x;
  if (i < NB * NH) hbuf[i] = f2bf(hidden[i]);  // hbuf[0] = h0 (bf16)
  if (i < 256) counters[i] = 0;
}

extern "C" void kernel_launch(void* const* d_in, const int* in_sizes, int n_in,
                              void* d_out, int out_size, void* d_ws, size_t ws_size,
                              hipStream_t stream) {
  (void)in_sizes; (void)n_in; (void)out_size; (void)ws_size;
  const float* x      = (const float*)d_in[0];
  const float* hidden = (const float*)d_in[1];
  const float* Wg     = (const float*)d_in[2];
  const float* Wc     = (const float*)d_in[3];
  const float* Wgh    = (const float*)d_in[4];
  const float* bg     = (const float*)d_in[5];
  const float* bc     = (const float*)d_in[6];
  const float* bgh    = (const float*)d_in[7];
  float* out = (float*)d_out;

  char* ws = (char*)d_ws;
  ushort_t* hbuf         = (ushort_t*)(ws);             // 2 * 128*1024 bf16 = 512 KB
  ushort_t* rsbuf        = (ushort_t*)(ws + 524288);    // 128*512 bf16 = 128 KB
  float*    ubuf         = (float*)(ws + 655360);       // 128*512 f32  = 256 KB
  unsigned int* counters = (unsigned int*)(ws + 917504);// 8 groups * 32 uints

  init_kernel<<<dim3(512), dim3(256), 0, stream>>>(hidden, hbuf, counters);
  ghost_gru_persistent<<<dim3(256), dim3(256), 0, stream>>>(
      x, hidden, Wg, Wc, Wgh, bg, bc, bgh, out, hbuf, rsbuf, ubuf, counters);
}

// Round 3
// 5811.308 us; speedup vs baseline: 3.0803x; 3.0803x over previous
//
#include <hip/hip_runtime.h>

// GhostGRU persistent-RNN kernel for MI355X (gfx950), round 2.
// Key change vs round 1: NO release/acquire fences anywhere (they emitted
// buffer_wbl2/buffer_inv = full per-XCD L2 writeback/invalidate per barrier per
// WG — the measured 30 us/step). All cross-WG traffic (h state, r_state, u,
// flags) now uses relaxed agent-scope atomics, which lower to sc0|sc1
// cache-bypass loads/stores meeting at the coherent LLC. Ordering: the
// vmcnt(0) drain inside __syncthreads before thread 0 posts the flag.

typedef unsigned short ushort_t;
typedef __attribute__((ext_vector_type(8))) short short8;   // 8 x bf16 (4 VGPRs)
typedef __attribute__((ext_vector_type(4))) float f32x4;

#define NB 128
#define NT 512
#define NF 256
#define NH 1024
#define KGATE 1280

#define AT_LOADU(p)    __hip_atomic_load((p), __ATOMIC_RELAXED, __HIP_MEMORY_SCOPE_AGENT)
#define AT_STOREU(p,v) __hip_atomic_store((p), (v), __ATOMIC_RELAXED, __HIP_MEMORY_SCOPE_AGENT)

__device__ __forceinline__ float bf2f(ushort_t u) {
  union { unsigned int i; float f; } v; v.i = ((unsigned int)u) << 16; return v.f;
}
__device__ __forceinline__ ushort_t f2bf(float f) {
  union { float f; unsigned int i; } v; v.f = f;
  unsigned int r = v.i + 0x7FFFu + ((v.i >> 16) & 1u);
  return (ushort_t)(r >> 16);
}
__device__ __forceinline__ float sigmoidf_(float x) { return 1.f / (1.f + __expf(-x)); }
__device__ __forceinline__ float tanhf_(float x) {
  float e = __expf(2.f * x); return 1.f - 2.f / (e + 1.f);
}

// Group barrier among 32 WGs: relaxed atomics only, zero cache-maintenance.
// __syncthreads drains vmcnt(0) => all this WG's bypass-stores are at the LLC
// before the flag increment becomes visible.
__device__ __forceinline__ void group_barrier(unsigned int* cnt, unsigned int target) {
  __syncthreads();
  if (threadIdx.x == 0) {
    __hip_atomic_fetch_add(cnt, 1u, __ATOMIC_RELAXED, __HIP_MEMORY_SCOPE_AGENT);
    while (AT_LOADU(cnt) < target) { }
  }
  __syncthreads();
}

__device__ __forceinline__ short8 pack_bf16_8(const float* p) {
  float4 a = *(const float4*)p;
  float4 b = *(const float4*)(p + 4);
  short8 f;
  f[0] = (short)f2bf(a.x); f[1] = (short)f2bf(a.y);
  f[2] = (short)f2bf(a.z); f[3] = (short)f2bf(a.w);
  f[4] = (short)f2bf(b.x); f[5] = (short)f2bf(b.y);
  f[6] = (short)f2bf(b.z); f[7] = (short)f2bf(b.w);
  return f;
}

__global__ void __launch_bounds__(256, 1) ghost_gru_persistent(
    const float* __restrict__ x, const float* __restrict__ hidden,
    const float* __restrict__ Wg, const float* __restrict__ Wc,
    const float* __restrict__ Wgh, const float* __restrict__ bg,
    const float* __restrict__ bc, const float* __restrict__ bgh,
    float* __restrict__ out, unsigned int* __restrict__ hbuf_u,
    unsigned int* __restrict__ rs_u, float* __restrict__ ubuf,
    unsigned int* __restrict__ counters)
{
  const int wgid = blockIdx.x;
  const int g    = wgid & 7;      // group (XCD-affine heuristic; perf only)
  const int memb = wgid >> 3;     // member 0..31 within group
  const int b0   = g * 16;        // batch base
  const int tid  = threadIdx.x;
  const int wv   = tid >> 6;      // wave 0..3
  const int lane = tid & 63;
  const int lq   = lane >> 4;     // quad 0..3
  const int ln   = lane & 15;
  unsigned int* cnt = counters + g * 32;

  // A-staging (bf16): [16 batches][ x(0..255) | ghost(256..767) | newh(768..1279) | rstate(1280..1791) | pad ]
  __shared__ ushort_t Abuf[16][1800];

  // VGPR-resident weight fragments: B-frag lane (n + 16q) holds W[n][kc*32 + 8q .. +7]
  short8 wfrag[40];
  int ncol0;
  float biasv;
  if (wv == 0 || wv == 1) {                    // gate: 32 cols per WG, 16 per wave
    ncol0 = memb * 32 + wv * 16;
    const float* wp = Wg + (size_t)(ncol0 + ln) * KGATE + lq * 8;
    #pragma unroll
    for (int kc = 0; kc < 40; ++kc) wfrag[kc] = pack_bf16_8(wp + kc * 32);
    biasv = bg[ncol0 + ln];
  } else if (wv == 2) {                        // candidate: 16 cols
    ncol0 = memb * 16;
    const float* wp = Wc + (size_t)(ncol0 + ln) * KGATE + lq * 8;
    #pragma unroll
    for (int kc = 0; kc < 40; ++kc) wfrag[kc] = pack_bf16_8(wp + kc * 32);
    biasv = bc[ncol0 + ln];
  } else {                                     // ghost: 16 cols, K=512
    ncol0 = memb * 16;
    const float* wp = Wgh + (size_t)(ncol0 + ln) * 512 + lq * 8;
    #pragma unroll
    for (int kc = 0; kc < 16; ++kc) wfrag[kc] = pack_bf16_8(wp + kc * 32);
    biasv = bgh[ncol0 + ln];
  }

  // fp32 master copy of new_h state, held by cand wave across all steps.
  float hreg[4];
  if (wv == 2) {
    #pragma unroll
    for (int r = 0; r < 4; ++r)
      hreg[r] = hidden[(size_t)(b0 + lq * 4 + r) * NH + 512 + ncol0 + ln];
  }

  #pragma unroll 1
  for (int t = 0; t < NT; ++t) {
    const int cur = t & 1, nxt = cur ^ 1;
    const unsigned* hsrc = hbuf_u + (size_t)cur * NB * 512;
    unsigned*       hdst = hbuf_u + (size_t)nxt * NB * 512;

    // ---- stage x_t (16x256 fp32 -> bf16, cached loads) ----
    #pragma unroll
    for (int k = 0; k < 4; ++k) {
      int i = tid + k * 256;
      int row = i >> 6, c4 = (i & 63) * 4;
      float4 v = *(const float4*)&x[((size_t)(b0 + row) * NT + t) * NF + c4];
      ushort4 u4 = make_ushort4(f2bf(v.x), f2bf(v.y), f2bf(v.z), f2bf(v.w));
      *(ushort4*)&Abuf[row][c4] = u4;
    }
    // ---- stage h = [ghost, newh] (16 x 512 uints, LLC-bypass loads) ----
    {
      unsigned hv[32];
      #pragma unroll
      for (int k = 0; k < 32; ++k) {
        int i = tid + k * 256;
        int row = i >> 9, c = i & 511;
        hv[k] = AT_LOADU(&hsrc[(size_t)(b0 + row) * 512 + c]);
      }
      #pragma unroll
      for (int k = 0; k < 32; ++k) {
        int i = tid + k * 256;
        int row = i >> 9, c = i & 511;
        *(unsigned*)&Abuf[row][256 + 2 * c] = hv[k];
      }
    }
    __syncthreads();

    // ---- phase 1: gate = sigmoid([x,ghost,newh] @ Wg^T + bg) ----
    if (wv < 2) {
      f32x4 acc0 = {0.f, 0.f, 0.f, 0.f}, acc1 = {0.f, 0.f, 0.f, 0.f};
      #pragma unroll
      for (int kc = 0; kc < 40; kc += 2) {
        short8 a0 = *(const short8*)&Abuf[ln][kc * 32 + lq * 8];
        acc0 = __builtin_amdgcn_mfma_f32_16x16x32_bf16(a0, wfrag[kc], acc0, 0, 0, 0);
        short8 a1 = *(const short8*)&Abuf[ln][(kc + 1) * 32 + lq * 8];
        acc1 = __builtin_amdgcn_mfma_f32_16x16x32_bf16(a1, wfrag[kc + 1], acc1, 0, 0, 0);
      }
      const int n = ncol0 + ln;
      if (ncol0 < 512) {  // r-gate -> rstate = r * h_old[newh part]
        #pragma unroll
        for (int r = 0; r < 4; ++r) {
          int row = lq * 4 + r;
          float s = sigmoidf_(acc0[r] + acc1[r] + biasv);
          float hold = bf2f(Abuf[row][768 + n]);
          unsigned hv = (unsigned)f2bf(s * hold);
          unsigned pv = (unsigned)__shfl_xor((int)hv, 1);
          if (!(ln & 1))
            AT_STOREU(&rs_u[(size_t)(b0 + row) * 256 + (n >> 1)], hv | (pv << 16));
        }
      } else {            // u-gate (fp32 for state update)
        #pragma unroll
        for (int r = 0; r < 4; ++r) {
          int row = lq * 4 + r;
          float s = sigmoidf_(acc0[r] + acc1[r] + biasv);
          AT_STOREU(&ubuf[(size_t)(b0 + row) * 512 + (n - 512)], s);
        }
      }
    }
    group_barrier(cnt, 32u * (3u * (unsigned)t + 1u));

    // prefetch u for cand wave (latency overlaps rstate staging)
    float uval[4];
    if (wv == 2) {
      #pragma unroll
      for (int r = 0; r < 4; ++r)
        uval[r] = AT_LOADU(&ubuf[(size_t)(b0 + lq * 4 + r) * 512 + ncol0 + ln]);
    }
    // ---- stage rstate (16 x 256 uints, LLC-bypass) ----
    {
      unsigned rv[16];
      #pragma unroll
      for (int k = 0; k < 16; ++k) {
        int i = tid + k * 256;
        int row = i >> 8, c = i & 255;
        rv[k] = AT_LOADU(&rs_u[(size_t)(b0 + row) * 256 + c]);
      }
      #pragma unroll
      for (int k = 0; k < 16; ++k) {
        int i = tid + k * 256;
        int row = i >> 8, c = i & 255;
        *(unsigned*)&Abuf[row][1280 + 2 * c] = rv[k];
      }
    }
    __syncthreads();

    // ---- phase 2: c = tanh([x,ghost,rstate] @ Wc^T + bc); new_h = u*h + (1-u)*c ----
    if (wv == 2) {
      f32x4 acc0 = {0.f, 0.f, 0.f, 0.f}, acc1 = {0.f, 0.f, 0.f, 0.f};
      #pragma unroll
      for (int kc = 0; kc < 40; kc += 2) {
        int base0 = (kc < 24) ? kc * 32 : 1280 + (kc - 24) * 32;
        int base1 = (kc + 1 < 24) ? (kc + 1) * 32 : 1280 + (kc + 1 - 24) * 32;
        short8 a0 = *(const short8*)&Abuf[ln][base0 + lq * 8];
        acc0 = __builtin_amdgcn_mfma_f32_16x16x32_bf16(a0, wfrag[kc], acc0, 0, 0, 0);
        short8 a1 = *(const short8*)&Abuf[ln][base1 + lq * 8];
        acc1 = __builtin_amdgcn_mfma_f32_16x16x32_bf16(a1, wfrag[kc + 1], acc1, 0, 0, 0);
      }
      const int n = ncol0 + ln;
      #pragma unroll
      for (int r = 0; r < 4; ++r) {
        int row = lq * 4 + r;
        int b = b0 + row;
        float cv = tanhf_(acc0[r] + acc1[r] + biasv);
        float u = uval[r];
        float hnew = u * hreg[r] + (1.f - u) * cv;
        hreg[r] = hnew;
        out[((size_t)b * NT + t) * NH + 512 + n] = hnew;
        unsigned hv = (unsigned)f2bf(hnew);
        unsigned pv = (unsigned)__shfl_xor((int)hv, 1);
        if (!(ln & 1))
          AT_STOREU(&hdst[(size_t)b * 512 + 256 + (n >> 1)], hv | (pv << 16));
        if (t == NT - 1) out[(size_t)NB * NT * NH + (size_t)b * NH + 512 + n] = hnew;
      }
    }
    group_barrier(cnt, 32u * (3u * (unsigned)t + 2u));

    // ---- stage fresh new_h (16 x 256 uints) into Abuf[.][768..1280) ----
    {
      unsigned nv[16];
      #pragma unroll
      for (int k = 0; k < 16; ++k) {
        int i = tid + k * 256;
        int row = i >> 8, c = i & 255;
        nv[k] = AT_LOADU(&hdst[(size_t)(b0 + row) * 512 + 256 + c]);
      }
      #pragma unroll
      for (int k = 0; k < 16; ++k) {
        int i = tid + k * 256;
        int row = i >> 8, c = i & 255;
        *(unsigned*)&Abuf[row][768 + 2 * c] = nv[k];
      }
    }
    __syncthreads();

    // ---- phase 3: ghost = tanh(new_h @ Wgh^T + bgh) ----
    if (wv == 3) {
      f32x4 acc = {0.f, 0.f, 0.f, 0.f};
      #pragma unroll
      for (int kc = 0; kc < 16; ++kc) {
        short8 a = *(const short8*)&Abuf[ln][768 + kc * 32 + lq * 8];
        acc = __builtin_amdgcn_mfma_f32_16x16x32_bf16(a, wfrag[kc], acc, 0, 0, 0);
      }
      const int n = ncol0 + ln;
      #pragma unroll
      for (int r = 0; r < 4; ++r) {
        int row = lq * 4 + r;
        int b = b0 + row;
        float gv = tanhf_(acc[r] + biasv);
        out[((size_t)b * NT + t) * NH + n] = gv;
        unsigned hv = (unsigned)f2bf(gv);
        unsigned pv = (unsigned)__shfl_xor((int)hv, 1);
        if (!(ln & 1))
          AT_STOREU(&hdst[(size_t)b * 512 + (n >> 1)], hv | (pv << 16));
        if (t == NT - 1) out[(size_t)NB * NT * NH + (size_t)b * NH + n] = gv;
      }
    }
    group_barrier(cnt, 32u * (3u * (unsigned)t + 3u));
  }
}

__global__ void init_kernel(const float* __restrict__ hidden,
                            unsigned int* __restrict__ hbuf_u,
                            unsigned int* __restrict__ counters) {
  int i = blockIdx.x * blockDim.x + threadIdx.x;
  if (i < NB * 512) {  // pack h0 into bf16 pairs; hbuf[0] = h0
    unsigned lo = (unsigned)f2bf(hidden[2 * i]);
    unsigned hi = (unsigned)f2bf(hidden[2 * i + 1]);
    hbuf_u[i] = lo | (hi << 16);
  }
  if (i < 256) counters[i] = 0;
}

extern "C" void kernel_launch(void* const* d_in, const int* in_sizes, int n_in,
                              void* d_out, int out_size, void* d_ws, size_t ws_size,
                              hipStream_t stream) {
  (void)in_sizes; (void)n_in; (void)out_size; (void)ws_size;
  const float* x      = (const float*)d_in[0];
  const float* hidden = (const float*)d_in[1];
  const float* Wg     = (const float*)d_in[2];
  const float* Wc     = (const float*)d_in[3];
  const float* Wgh    = (const float*)d_in[4];
  const float* bg     = (const float*)d_in[5];
  const float* bc     = (const float*)d_in[6];
  const float* bgh    = (const float*)d_in[7];
  float* out = (float*)d_out;

  char* ws = (char*)d_ws;
  unsigned int* hbuf_u   = (unsigned int*)(ws);         // 2 * 128*512 uints = 512 KB
  unsigned int* rs_u     = (unsigned int*)(ws + 524288);// 128*256 uints = 128 KB
  float*        ubuf     = (float*)(ws + 655360);       // 128*512 f32  = 256 KB
  unsigned int* counters = (unsigned int*)(ws + 917504);// 8 groups * 32 uints

  init_kernel<<<dim3(256), dim3(256), 0, stream>>>(hidden, hbuf_u, counters);
  ghost_gru_persistent<<<dim3(256), dim3(256), 0, stream>>>(
      x, hidden, Wg, Wc, Wgh, bg, bc, bgh, out, hbuf_u, rs_u, ubuf, counters);
}